// Round 9
// baseline (381.349 us; speedup 1.0000x reference)
//
#include <hip/hip_runtime.h>

#define NN 50000
#define NE 800000
#define REP 8                 // counter replicas per node (breaks same-address RMW recurrence)
#define SCAN_N (2 * NN * REP) // 800000 combined bins: [dst NN*8 | src NN*8]

__device__ __forceinline__ float sigm(float v) { return 1.0f / (1.0f + __expf(-v)); }

// ===========================================================================
// Hierarchical exclusive scan over SCAN_N elements, 2048 elems/block.
// ===========================================================================
__global__ void scan_k1(const int* __restrict__ cnt, int n,
                        int* __restrict__ bsum)
{
    __shared__ int s[256];
    int t = threadIdx.x;
    int base = blockIdx.x * 2048 + t * 8;
    int sum = 0;
#pragma unroll
    for (int q = 0; q < 8; ++q) {
        int idx = base + q;
        if (idx < n) sum += cnt[idx];
    }
    s[t] = sum;
    __syncthreads();
#pragma unroll
    for (int d = 128; d; d >>= 1) {
        if (t < d) s[t] += s[t + d];
        __syncthreads();
    }
    if (t == 0) bsum[blockIdx.x] = s[0];
}

__global__ void scan_k2(int* __restrict__ bsum, int nblocks)
{
    __shared__ int s[512];
    int t = threadIdx.x;
    int v = (t < nblocks) ? bsum[t] : 0;
    s[t] = v;
    __syncthreads();
#pragma unroll
    for (int d = 1; d < 512; d <<= 1) {
        int a = (t >= d) ? s[t - d] : 0;
        __syncthreads();
        s[t] += a;
        __syncthreads();
    }
    if (t < nblocks) bsum[t] = s[t] - v;   // exclusive
}

__global__ void scan_k3(const int* __restrict__ cnt, int n,
                        const int* __restrict__ bsum,
                        int* __restrict__ offset)
{
    __shared__ int s[256];
    int t = threadIdx.x;
    int base = blockIdx.x * 2048 + t * 8;
    int v[8];
    int sum = 0;
#pragma unroll
    for (int q = 0; q < 8; ++q) {
        int idx = base + q;
        v[q] = (idx < n) ? cnt[idx] : 0;
        sum += v[q];
    }
    s[t] = sum;
    __syncthreads();
#pragma unroll
    for (int d = 1; d < 256; d <<= 1) {
        int a = (t >= d) ? s[t - d] : 0;
        __syncthreads();
        s[t] += a;
        __syncthreads();
    }
    int run = bsum[blockIdx.x] + ((t > 0) ? s[t - 1] : 0);
#pragma unroll
    for (int q = 0; q < 8; ++q) {
        int idx = base + q;
        if (idx <= n) offset[idx] = run;
        run += v[q];
    }
}

// ===========================================================================
// Graph prep. bin(dst) = d*8 + r, bin(src) = NN*8 + s*8 + r, r = wave&7.
// Replication drops per-address RMW aliasing from ~16 to ~2.
// ranks < max degree (~45) -> u16.
// ===========================================================================
__global__ void build_ranks(const int* __restrict__ ei,
                            int* __restrict__ cnt,
                            unsigned short* __restrict__ rank_s,
                            unsigned short* __restrict__ rank_d)
{
    int e = blockIdx.x * 256 + threadIdx.x;   // NE == 3125*256 exactly
    int r = (e >> 6) & (REP - 1);
    int s = ei[e], d = ei[NE + e];
    rank_d[e] = (unsigned short)atomicAdd(cnt + d * REP + r, 1);
    rank_s[e] = (unsigned short)atomicAdd(cnt + NN * REP + s * REP + r, 1);
}

// pack[pos] = (src << 20) | dstpos  (src < 2^16, dstpos < 2^20).
__global__ void build_perm(const int* __restrict__ ei,
                           const float* __restrict__ ea,
                           const int* __restrict__ off_all,
                           const unsigned short* __restrict__ rank_s,
                           const unsigned short* __restrict__ rank_d,
                           unsigned long long* __restrict__ pack,
                           float* __restrict__ ea_s)
{
    int e = blockIdx.x * 256 + threadIdx.x;
    int r = (e >> 6) & (REP - 1);
    int s = ei[e], d = ei[NE + e];
    int pos = off_all[NN * REP + s * REP + r] - NE + (int)rank_s[e];
    int dp  = off_all[d * REP + r] + (int)rank_d[e];
    pack[pos] = ((unsigned long long)s << 20) | (unsigned long long)dp;
    ((float4*)ea_s)[pos] = ((const float4*)ea)[e];
}

// ===========================================================================
// Per-node: G[(k*4+ob)][n] (float4 over o) = sum_i x[n][i]*eW2[k][i*16+o..+3]
//           xb[ob][n] = sum_i x[n][i]*eb2[i*16+o..]
// ===========================================================================
template<int DIN>
__global__ __launch_bounds__(256) void precompute_G(
        const float* __restrict__ x,
        const float* __restrict__ eW2,   // [16][DIN*16]
        const float* __restrict__ eb2,   // [DIN*16]
        float* __restrict__ G,           // float4 [64][NN]
        float* __restrict__ xb)          // float4 [4][NN]
{
    __shared__ __align__(16) float w2L[16 * DIN * 16];
    __shared__ __align__(16) float b2L[DIN * 16];
    int tid = threadIdx.x;
    for (int i = tid; i < 16 * DIN * 16; i += 256) w2L[i] = eW2[i];
    for (int i = tid; i < DIN * 16; i += 256) b2L[i] = eb2[i];
    __syncthreads();

    int n = blockIdx.x * 256 + tid;
    if (n >= NN) return;
    float xi[DIN];
#pragma unroll
    for (int i4 = 0; i4 < DIN / 4; ++i4)
        ((float4*)xi)[i4] = ((const float4*)(x + (size_t)n * DIN))[i4];

    const float4* w2v = (const float4*)w2L;
    const float4* b2v = (const float4*)b2L;
    float4* Gv  = (float4*)G;
    float4* xbv = (float4*)xb;

#pragma unroll
    for (int ob = 0; ob < 4; ++ob) {
        float4 acc = make_float4(0.f, 0.f, 0.f, 0.f);
#pragma unroll
        for (int i = 0; i < DIN; ++i) {
            float4 b = b2v[i * 4 + ob];
            acc.x += xi[i] * b.x; acc.y += xi[i] * b.y;
            acc.z += xi[i] * b.z; acc.w += xi[i] * b.w;
        }
        xbv[(size_t)ob * NN + n] = acc;
    }
#pragma unroll 1
    for (int k = 0; k < 16; ++k) {
#pragma unroll
        for (int ob = 0; ob < 4; ++ob) {
            float4 acc = make_float4(0.f, 0.f, 0.f, 0.f);
#pragma unroll
            for (int i = 0; i < DIN; ++i) {
                float4 w = w2v[(k * DIN + i) * 4 + ob];
                acc.x += xi[i] * w.x; acc.y += xi[i] * w.y;
                acc.z += xi[i] * w.z; acc.w += xi[i] * w.w;
            }
            Gv[(size_t)(k * 4 + ob) * NN + n] = acc;
        }
    }
}

// ===========================================================================
// Edge message, src-sorted: msg = xb[src] + sum_k h[k]*G[k][src];
// scatter-store 64B row to dst-sorted slot. No atomics.
// ===========================================================================
__global__ __launch_bounds__(256) void edge_msg(
        const unsigned long long* __restrict__ pack,  // [NE] (src<<20)|dstpos
        const float* __restrict__ ea_s,   // [NE][4] (src-sorted)
        const float* __restrict__ eW1,    // [4][16]
        const float* __restrict__ eb1,    // [16]
        const float* __restrict__ G,      // float4 [64][NN]
        const float* __restrict__ xb,     // float4 [4][NN]
        float* __restrict__ msgbuf)       // [NE][16]
{
    __shared__ __align__(16) float4 w1t[16];  // w1t[j] = eW1[:,j]
    __shared__ __align__(16) float  b1s[16];
    int tid = threadIdx.x;
    if (tid < 16) {
        w1t[tid] = make_float4(eW1[tid], eW1[16 + tid], eW1[32 + tid], eW1[48 + tid]);
        b1s[tid] = eb1[tid];
    }
    __syncthreads();

    int pos = blockIdx.x * 256 + tid;
    unsigned long long pk = pack[pos];
    int dp  = (int)(pk & 0xFFFFFu);
    int src = (int)(pk >> 20);
    float4 a = ((const float4*)ea_s)[pos];

    float h[16];
#pragma unroll
    for (int j = 0; j < 16; ++j) {
        float4 w = w1t[j];
        float p = b1s[j] + a.x * w.x + a.y * w.y + a.z * w.z + a.w * w.w;
        h[j] = p * sigm(p);
    }

    const float4* Gv  = (const float4*)G;
    const float4* xbv = (const float4*)xb;
    float4 acc[4];
#pragma unroll
    for (int ob = 0; ob < 4; ++ob) acc[ob] = xbv[(size_t)ob * NN + src];
#pragma unroll
    for (int k = 0; k < 16; ++k) {
        float hk = h[k];
#pragma unroll
        for (int ob = 0; ob < 4; ++ob) {
            float4 g = Gv[(size_t)(k * 4 + ob) * NN + src];
            acc[ob].x += hk * g.x; acc[ob].y += hk * g.y;
            acc[ob].z += hk * g.z; acc[ob].w += hk * g.w;
        }
    }
    float4* mrow = (float4*)(msgbuf + (size_t)dp * 16);
#pragma unroll
    for (int ob = 0; ob < 4; ++ob) mrow[ob] = acc[ob];
}

// ===========================================================================
// Gather: 16-lane group per node sums its contiguous msg rows (coalesced,
// no atomics), then fused node update (+ output MLP when FINAL).
// Node n's dst range: [off_all[8n], off_all[8(n+1)]) (replica bins node-major).
// ===========================================================================
template<int DIN, bool FINAL>
__global__ __launch_bounds__(256) void gather_nodes(
        const float* __restrict__ xin,    // [NN][DIN]
        const float* __restrict__ root,   // [DIN][16]
        const float* __restrict__ bias,   // [16]
        const int*   __restrict__ offset, // off_all (replicated bins)
        const float* __restrict__ msgbuf, // [NE][16]
        const float* __restrict__ mW1,    // [16][16] (FINAL)
        const float* __restrict__ mb1,    // [16]
        const float* __restrict__ mW2,    // [16]
        const float* __restrict__ mb2,    // [1]
        float* __restrict__ xout)         // [NN][16] or [NN]
{
    __shared__ __align__(16) float rootL[DIN * 16];
    __shared__ __align__(16) float biasL[16];
    __shared__ __align__(16) float w1m[256];
    __shared__ __align__(16) float b1m[16];
    __shared__ __align__(16) float w2m[16];
    __shared__ float b2m;
    int tid = threadIdx.x;
    for (int i = tid; i < DIN * 16; i += 256) rootL[i] = root[i];
    if (tid < 16) biasL[tid] = bias[tid];
    if constexpr (FINAL) {
        w1m[tid] = mW1[tid];
        if (tid < 16) { b1m[tid] = mb1[tid]; w2m[tid] = mW2[tid]; }
        if (tid == 0) b2m = mb2[0];
    }
    __syncthreads();

    int ch = tid & 15;
    int n  = blockIdx.x * 16 + (tid >> 4);   // NN == 3125*16 exactly
    int s  = offset[n * REP];
    int epos = offset[(n + 1) * REP];
    int deg = epos - s;

    float acc = 0.f;
    for (int j = s; j < epos; ++j)
        acc += msgbuf[(size_t)j * 16 + ch];

    float v = acc / fmaxf((float)deg, 1.0f) + biasL[ch];
#pragma unroll
    for (int i = 0; i < DIN; ++i)
        v += xin[(size_t)n * DIN + i] * rootL[i * 16 + ch];
    v = fmaxf(v, 0.f);

    if constexpr (!FINAL) {
        xout[(size_t)n * 16 + ch] = v;
    } else {
        float z = b1m[ch];
#pragma unroll
        for (int o = 0; o < 16; ++o) {
            float vo = __shfl(v, o, 16);
            z += vo * w1m[o * 16 + ch];
        }
        float ss = z * sigm(z) * w2m[ch];
#pragma unroll
        for (int off = 8; off; off >>= 1) ss += __shfl_xor(ss, off, 16);
        if (ch == 0) xout[n] = sigm(ss + b2m);
    }
}

// ===========================================================================
// Host launch
// ===========================================================================
extern "C" void kernel_launch(void* const* d_in, const int* in_sizes, int n_in,
                              void* d_out, int out_size, void* d_ws, size_t ws_size,
                              hipStream_t stream) {
    const float* x     = (const float*)d_in[0];
    const int*   ei    = (const int*)  d_in[1];
    const float* ea    = (const float*)d_in[2];
    const float* eW1_0 = (const float*)d_in[3];
    const float* eb1_0 = (const float*)d_in[4];
    const float* eW2_0 = (const float*)d_in[5];
    const float* eb2_0 = (const float*)d_in[6];
    const float* root0 = (const float*)d_in[7];
    const float* bias0 = (const float*)d_in[8];
    const float* eW1_1 = (const float*)d_in[9];
    const float* eb1_1 = (const float*)d_in[10];
    const float* eW2_1 = (const float*)d_in[11];
    const float* eb2_1 = (const float*)d_in[12];
    const float* root1 = (const float*)d_in[13];
    const float* bias1 = (const float*)d_in[14];
    const float* mW1   = (const float*)d_in[15];
    const float* mb1   = (const float*)d_in[16];
    const float* mW2   = (const float*)d_in[17];
    const float* mb2   = (const float*)d_in[18];
    float* out = (float*)d_out;

    const int EG = NE / 256;          // 3125
    const int GG = NN / 16;           // 3125
    const int PG = (NN + 255) / 256;  // 196
    const int SB = (SCAN_N + 2047) / 2048;  // 391

    // ---- ws layout (4B words), total 33,600,516 words = 134.4 MB ----
    int* W = (int*)d_ws;
    int*   off_all = W;                      // [0, 800002) -> pad to 800004
    int*   bsum    = W + 800004;             // 512
    unsigned short* rank_s = (unsigned short*)(W + 800516);   // NE u16 = 400000 w
    unsigned short* rank_d = (unsigned short*)(W + 1200516);  // NE u16 = 400000 w
    unsigned long long* pack = (unsigned long long*)(W + 1600516); // NE u64 = 1.6M w
    float* x1      = (float*)(W + 3200516);  // [NN][16]       = 800000 w
    float* ea_s    = (float*)(W + 4000516);  // [NE][4]        = 3.2M w
    float* xbuf    = (float*)(W + 7200516);  // float4 [4][NN] = 800000 w
    float* G       = (float*)(W + 8000516);  // float4 [64][NN]= 12.8M w
    float* msgbuf  = (float*)(W + 20800516); // [NE][16]       = 12.8M w
    // transient counters overlaid on msgbuf (dead before msgbuf written):
    int*   cnt     = W + 20800516;           // SCAN_N ints

    hipMemsetAsync(cnt, 0, SCAN_N * sizeof(int), stream);
    build_ranks<<<EG, 256, 0, stream>>>(ei, cnt, rank_s, rank_d);
    scan_k1<<<SB, 256, 0, stream>>>(cnt, SCAN_N, bsum);
    scan_k2<<<1, 512, 0, stream>>>(bsum, SB);
    scan_k3<<<SB, 256, 0, stream>>>(cnt, SCAN_N, bsum, off_all);
    build_perm<<<EG, 256, 0, stream>>>(ei, ea, off_all, rank_s, rank_d, pack, ea_s);

    // ---- layer 0 ----
    precompute_G<8><<<PG, 256, 0, stream>>>(x, eW2_0, eb2_0, G, xbuf);
    edge_msg<<<EG, 256, 0, stream>>>(pack, ea_s, eW1_0, eb1_0, G, xbuf, msgbuf);
    gather_nodes<8, false><<<GG, 256, 0, stream>>>(x, root0, bias0, off_all, msgbuf,
                                                   mW1, mb1, mW2, mb2, x1);
    // ---- layer 1 ----
    precompute_G<16><<<PG, 256, 0, stream>>>(x1, eW2_1, eb2_1, G, xbuf);
    edge_msg<<<EG, 256, 0, stream>>>(pack, ea_s, eW1_1, eb1_1, G, xbuf, msgbuf);
    gather_nodes<16, true><<<GG, 256, 0, stream>>>(x1, root1, bias1, off_all, msgbuf,
                                                   mW1, mb1, mW2, mb2, out);
}